// Round 11
// baseline (154.773 us; speedup 1.0000x reference)
//
#include <hip/hip_runtime.h>
#include <hip/hip_bf16.h>
#include <math.h>

#define NN    10000
#define HIDD  512
#define BP    4096
#define KPAD  10048     // 157 * 64 (fp8 gather GEMM, BK=64)
#define NK    157
#define KSPLIT 5
#define ASCALE 16.0f
#define BSCALE 64.0f
#define INVSC  0.0009765625f   // 1/(16*64)

typedef short bf16x8 __attribute__((ext_vector_type(8)));
typedef float f32x4  __attribute__((ext_vector_type(4)));
typedef unsigned short u16x4 __attribute__((ext_vector_type(4)));
typedef unsigned short u16x8 __attribute__((ext_vector_type(8)));
typedef int   i32x4  __attribute__((ext_vector_type(4)));

__device__ __forceinline__ unsigned short f2bf(float f) {
  union { float f; unsigned u; } v; v.f = f;
  unsigned r = v.u + 0x7FFFu + ((v.u >> 16) & 1u);   // RN-even
  return (unsigned short)(r >> 16);
}
__device__ __forceinline__ float bf2f(unsigned short u) {
  union { unsigned u; float f; } v; v.u = ((unsigned)u) << 16;
  return v.f;
}
__device__ __forceinline__ void gload_lds16(const void* g, void* l) {
  __builtin_amdgcn_global_load_lds((const __attribute__((address_space(1))) unsigned int*)g,
                                   (__attribute__((address_space(3))) unsigned int*)l, 16, 0, 0);
}

// pack 2 f32 -> 2 fp8 e4m3 into low (hi=false) or high (hi=true) 16 bits of `old`
__device__ __forceinline__ int f2fp8pair(float a, float b, int old, bool hi) {
#if __has_builtin(__builtin_amdgcn_cvt_pk_fp8_f32)
  return hi ? __builtin_amdgcn_cvt_pk_fp8_f32(a, b, old, true)
            : __builtin_amdgcn_cvt_pk_fp8_f32(a, b, old, false);
#else
  auto cv = [](float x) -> unsigned {
    float c = fminf(fmaxf(x, -448.f), 448.f);
    union { float f; unsigned u; } v; v.f = c;
    unsigned sign = (v.u >> 24) & 0x80u;
    unsigned absu = v.u & 0x7FFFFFFFu;
    if (absu < 0x3B800000u) {
      int q = (int)rintf(fabsf(c) * 512.f);
      if (q > 7) q = 7;
      return sign | (unsigned)q;
    }
    unsigned r = absu + 0x00080000u + ((absu >> 20) & 1u);
    int e = (int)((r >> 23) & 0xFF) - 127;
    unsigned m = (r >> 20) & 7u;
    if (e > 8) return sign | 0x7Eu;
    if (e < -6) { int q = (int)rintf(fabsf(c) * 512.f); if (q > 7) q = 7; return sign | (unsigned)q; }
    return sign | ((unsigned)(e + 7) << 3) | m;
  };
  unsigned w = cv(a) | (cv(b) << 8);
  return hi ? ((old & 0xFFFF) | (int)(w << 16)) : (int)(((unsigned)old & 0xFFFF0000u) | w);
#endif
}

// ---- single-kernel dedup: LDS byte flags -> mark -> scan -> compact ----
__global__ __launch_bounds__(1024)
void dedup_all(const int* __restrict__ idxx, const int* __restrict__ idxy,
               int* __restrict__ newpos, int* __restrict__ rows, int* __restrict__ nuniq) {
  __shared__ unsigned char flag[10240];
  __shared__ int part[1024];
  int t = threadIdx.x;
  #pragma unroll
  for (int j = 0; j < 3; ++j) {
    int w = t + j * 1024;
    if (w < 2560) ((int*)flag)[w] = 0;
  }
  __syncthreads();
  #pragma unroll
  for (int j = 0; j < 4; ++j) {
    flag[idxx[t + j * 1024]] = 1;
    flag[idxy[t + j * 1024]] = 1;
  }
  __syncthreads();
  int base = t * 10;
  int loc[10]; int s = 0;
  #pragma unroll
  for (int j = 0; j < 10; ++j) {
    int f = (base + j < NN) ? (int)flag[base + j] : 0;
    loc[j] = s; s += f;
  }
  part[t] = s;
  __syncthreads();
  for (int off = 1; off < 1024; off <<= 1) {
    int v = (t >= off) ? part[t - off] : 0;
    __syncthreads();
    part[t] += v;
    __syncthreads();
  }
  int pre = (t == 0) ? 0 : part[t - 1];
  #pragma unroll
  for (int j = 0; j < 10; ++j) {
    int idx = base + j;
    if (idx < NN) {
      int pos = pre + loc[j];
      newpos[idx] = pos;
      if (flag[idx]) rows[pos] = idx;
    }
  }
  if (t == 1023) nuniq[0] = part[1023];
}

// Merged weight prep (flattened 1-D grid, 256 threads):
//  bid < 5024            : W1 f32 [NN][512] -> fp8 e4m3 (x BSCALE) [512][KPAD]
//  bid >= 5024 (1024 bl) : 4x 512x512 transpose+cvt bf16 (highway weights)
__global__ void prep_weights(const float* __restrict__ W1, unsigned char* __restrict__ W1T8,
                             const float* __restrict__ s0, const float* __restrict__ s1,
                             const float* __restrict__ s2, const float* __restrict__ s3,
                             unsigned short* __restrict__ d0, unsigned short* __restrict__ d1,
                             unsigned short* __restrict__ d2, unsigned short* __restrict__ d3) {
  __shared__ float tile[32][33];
  int bid = blockIdx.x;
  int t = threadIdx.x, c = t & 31, r = t >> 5;
  if (bid < 5024) {                       // W1 -> fp8: 314 k-tiles x 16 n-tiles
    int k0 = (bid % 314) * 32, n0 = (bid / 314) * 32;
    #pragma unroll
    for (int i = 0; i < 4; ++i) {
      int k = k0 + r + i * 8;
      tile[r + i * 8][c] = (k < NN) ? W1[(size_t)k * 512 + (n0 + c)] : 0.f;
    }
    __syncthreads();
    int c2 = t & 15, rn = t >> 4;
    #pragma unroll
    for (int i = 0; i < 2; ++i) {
      int n = rn + i * 16;
      int w = f2fp8pair(tile[2 * c2][n] * BSCALE, tile[2 * c2 + 1][n] * BSCALE, 0, false);
      *(unsigned short*)(W1T8 + (size_t)(n0 + n) * KPAD + k0 + 2 * c2) = (unsigned short)(w & 0xFFFF);
    }
  } else {                                // highway weights -> bf16 transpose
    int q = bid - 5024;
    int wsel = q >> 8, rr2 = q & 255;
    const float* src = (wsel == 0) ? s0 : (wsel == 1) ? s1 : (wsel == 2) ? s2 : s3;
    unsigned short* dst = (wsel == 0) ? d0 : (wsel == 1) ? d1 : (wsel == 2) ? d2 : d3;
    int k0 = (rr2 & 15) * 32, n0 = (rr2 >> 4) * 32;
    #pragma unroll
    for (int i = 0; i < 4; ++i)
      tile[r + i * 8][c] = src[(size_t)(k0 + r + i * 8) * 512 + (n0 + c)];
    __syncthreads();
    #pragma unroll
    for (int i = 0; i < 4; ++i)
      dst[(size_t)(n0 + r + i * 8) * 512 + (k0 + c)] = f2bf(tile[c][r + i * 8]);
  }
}

// FP8 Gather-GEMM, fully double-buffered, ONE barrier per K-iteration.
// Ppart[ksp][row][512] (bf16) = (A[rows]*16) @ (W1T*64)^T over K-chunk ksp.
// Tile 64m x 512n x BK=64 fp8; 512 threads = 8 waves, wave-tile 64x64.
// LDS: As 2x4KB + Bs 2x32KB = 72KB -> 2 blocks/CU.
// Per iter: issue B(t+1)/A(t+1) at compute start -> they fly under the whole
// MFMA+WRITEA phase; single end barrier drains and publishes. No per-iter
// exposed load latency (the round-5/round-10 flaw).
__global__ __launch_bounds__(512, 4)
void gather_gemm(const float* __restrict__ A, const unsigned char* __restrict__ BT8,
                 unsigned short* __restrict__ Ppart,
                 const int* __restrict__ rows, const int* __restrict__ nuniq_p) {
  __shared__ __align__(16) char As[2][64 * 64];     // 64 rows x 64 fp8, 4 granules/row, XOR swz
  __shared__ __align__(16) char Bs[2][512 * 64];    // 512 n-rows x 64 fp8
  const int nuniq = nuniq_p[0];
  const int m0 = blockIdx.y * 64;
  if (m0 >= nuniq) return;
  const int tid  = threadIdx.x;
  const int lane = tid & 63;
  const int wave = tid >> 6;            // 0..7, owns n-range [wave*64, +64)
  const int ksp  = blockIdx.x;          // 0..KSPLIT-1
  const int t0   = (ksp * NK) / KSPLIT;
  const int t1   = ((ksp + 1) * NK) / KSPLIT;

  // A staging: 8 threads/row, each 8 consecutive floats -> 8 fp8 (8B slot)
  const int sr = tid >> 3, sp = tid & 7;       // slot sp: granule sp>>1, half sp&1
  int m = m0 + sr;
  int g = rows[(m < nuniq) ? m : (nuniq - 1)];
  const float* arow = A + (size_t)g * NN;
  const int aswz = (((sp >> 1) ^ (sr & 3)) << 4) + ((sp & 1) << 3);

  // B staging: per wave 4 gload_lds chunks of 1KB (16 rows of 64B); lane covers
  // row chunk*16 + (lane>>2); LDS 16B slot lane&3 <- global granule (lane&3)^(row&3)
  const unsigned char* bsrc0 =
      BT8 + (size_t)((wave << 6) + (lane >> 2)) * KPAD + ((((lane & 3) ^ ((lane >> 2) & 3))) << 4);
  const int bofs = (wave << 12);

  f32x4 acc[4][4];
  #pragma unroll
  for (int i = 0; i < 4; ++i)
    #pragma unroll
    for (int j = 0; j < 4; ++j) acc[i][j] = (f32x4){0.f, 0.f, 0.f, 0.f};

  float4 ar[2];

  auto LOADA = [&](int t) {
    int ka = t * 64 + sp * 8;
    if (ka < NN) {
      ar[0] = *(const float4*)(arow + ka);
      ar[1] = *(const float4*)(arow + ka + 4);
    } else {
      ar[0] = make_float4(0.f, 0.f, 0.f, 0.f);
      ar[1] = make_float4(0.f, 0.f, 0.f, 0.f);
    }
  };
  auto ISSUEB = [&](int t, int buf) {
    const unsigned char* s = bsrc0 + (size_t)t * 64;
    char* d = Bs[buf] + bofs;
    #pragma unroll
    for (int j = 0; j < 4; ++j)
      gload_lds16(s + (size_t)j * 16 * KPAD, d + j * 1024);
  };
  auto WRITEA = [&](int buf) {
    int w = f2fp8pair(ar[0].x * ASCALE, ar[0].y * ASCALE, 0, false);
    w     = f2fp8pair(ar[0].z * ASCALE, ar[0].w * ASCALE, w, true);
    int w2 = f2fp8pair(ar[1].x * ASCALE, ar[1].y * ASCALE, 0, false);
    w2     = f2fp8pair(ar[1].z * ASCALE, ar[1].w * ASCALE, w2, true);
    *(int*)(As[buf] + sr * 64 + aswz) = w;
    // second 4 floats share the same 8B slot?  No: sp covers 8 floats -> 8 fp8 = 8B.
    // w holds first 4, w2 second 4 -> write as two ints at slot and slot+4.
    *(int*)(As[buf] + sr * 64 + aswz + 4) = w2;
  };

  // prologue
  LOADA(t0);
  ISSUEB(t0, 0);
  WRITEA(0);                           // waits A(t0) regs
  __syncthreads();                     // drains B(t0); As[0] visible
  int cur = 0;
  for (int t = t0; t < t1; ++t) {
    const bool more = (t + 1 < t1);
    if (more) {
      ISSUEB(t + 1, cur ^ 1);          // fly under compute
      LOADA(t + 1);
    }
    const char* Ac = As[cur];
    const char* Bc = Bs[cur];
    #pragma unroll
    for (int ks = 0; ks < 2; ++ks) {   // 2 x K=32 sections
      int kq  = lane >> 4;             // 0..3
      int G   = ks * 2 + (kq >> 1);    // granule 0..3
      int inn = (kq & 1) << 3;
      long aL[4]; long bL[4];
      #pragma unroll
      for (int i = 0; i < 4; ++i) {
        int r = i * 16 + (lane & 15);
        aL[i] = *(const long*)(Ac + r * 64 + ((G ^ (r & 3)) << 4) + inn);
      }
      #pragma unroll
      for (int j = 0; j < 4; ++j) {
        int n = wave * 64 + j * 16 + (lane & 15);
        bL[j] = *(const long*)(Bc + n * 64 + ((G ^ (n & 3)) << 4) + inn);
      }
      #pragma unroll
      for (int i = 0; i < 4; ++i)
        #pragma unroll
        for (int j = 0; j < 4; ++j)
          acc[i][j] = __builtin_amdgcn_mfma_f32_16x16x32_fp8_fp8(aL[i], bL[j], acc[i][j], 0, 0, 0);
    }
    if (more) WRITEA(cur ^ 1);         // waits A(t+1) regs (covered by compute)
    __syncthreads();                   // drains B(t+1); publishes As/Bs[cur^1]; readers done
    cur ^= 1;
  }

  unsigned short* Cb = Ppart + (size_t)ksp * (8192 * 512);
  #pragma unroll
  for (int i = 0; i < 4; ++i) {
    #pragma unroll
    for (int j = 0; j < 4; ++j) {
      int row = m0 + i * 16 + ((lane >> 4) << 2);
      int col = wave * 64 + j * 16 + (lane & 15);
      #pragma unroll
      for (int rr = 0; rr < 4; ++rr)
        Cb[(size_t)(row + rr) * 512 + col] = f2bf(acc[i][j][rr]);
    }
  }
}

// Fused highway layer (bf16)
__global__ __launch_bounds__(256)
void hwy_gemm(const unsigned short* __restrict__ xin, const unsigned short* __restrict__ WcT,
              const float* __restrict__ bh, const float* __restrict__ bg,
              unsigned short* __restrict__ xout) {
  __shared__ __align__(16) char As[128 * 128];
  __shared__ __align__(16) char Bs[128 * 128];
  const int tid  = threadIdx.x;
  const int lane = tid & 63;
  const int wave = tid >> 6;
  const int wm = wave >> 1, wn = wave & 1;
  const int m0 = blockIdx.y * 128;
  const int n0 = blockIdx.x * 64;

  const int sr = tid >> 1, sp = tid & 1;
  const unsigned short* arow16 = xin + (size_t)(m0 + sr) * HIDD;
  const int rb = tid >> 1;
  const int grow = (rb < 64) ? (n0 + rb) : (512 + n0 + rb - 64);
  const unsigned short* brow = WcT + (size_t)grow * HIDD;

  f32x4 acc[4][2][2];
  #pragma unroll
  for (int i = 0; i < 4; ++i)
    #pragma unroll
    for (int j = 0; j < 2; ++j)
      #pragma unroll
      for (int p = 0; p < 2; ++p) acc[i][j][p] = (f32x4){0.f, 0.f, 0.f, 0.f};

  u16x8 ar16[4], br16[4];

  auto LOADREGS = [&](int t) {
    int k0 = t * 64;
    #pragma unroll
    for (int j = 0; j < 4; ++j)
      ar16[j] = *(const u16x8*)(arow16 + k0 + (sp * 4 + j) * 8);
    #pragma unroll
    for (int q = 0; q < 4; ++q)
      br16[q] = *(const u16x8*)(brow + k0 + (sp * 4 + q) * 8);
  };
  auto WRITELDS = [&]() {
    #pragma unroll
    for (int j = 0; j < 4; ++j) {
      int gq = sp * 4 + j;
      *(u16x8*)(As + sr * 128 + ((gq ^ (sr & 7)) << 4)) = ar16[j];
    }
    #pragma unroll
    for (int q = 0; q < 4; ++q) {
      int gq = sp * 4 + q;
      *(u16x8*)(Bs + rb * 128 + ((gq ^ (rb & 7)) << 4)) = br16[q];
    }
  };

  for (int t = 0; t < 8; ++t) {
    if (t == 0) LOADREGS(0);
    else __syncthreads();
    WRITELDS();
    if (t + 1 < 8) LOADREGS(t + 1);
    __syncthreads();
    #pragma unroll
    for (int ks = 0; ks < 2; ++ks) {
      bf16x8 af[4]; bf16x8 bfr[2][2];
      int kg = ks * 4 + (lane >> 4);
      #pragma unroll
      for (int i = 0; i < 4; ++i) {
        int r = wm * 64 + i * 16 + (lane & 15);
        af[i] = *(const bf16x8*)(As + r * 128 + ((kg ^ (r & 7)) << 4));
      }
      #pragma unroll
      for (int j = 0; j < 2; ++j)
        #pragma unroll
        for (int p = 0; p < 2; ++p) {
          int n = p * 64 + wn * 32 + j * 16 + (lane & 15);
          bfr[j][p] = *(const bf16x8*)(Bs + n * 128 + ((kg ^ (n & 7)) << 4));
        }
      #pragma unroll
      for (int i = 0; i < 4; ++i)
        #pragma unroll
        for (int j = 0; j < 2; ++j)
          #pragma unroll
          for (int p = 0; p < 2; ++p)
            acc[i][j][p] = __builtin_amdgcn_mfma_f32_16x16x32_bf16(af[i], bfr[j][p], acc[i][j][p], 0, 0, 0);
    }
  }

  #pragma unroll
  for (int j = 0; j < 2; ++j) {
    int col = n0 + wn * 32 + j * 16 + (lane & 15);
    float bhv = bh[col], bgv = bg[col];
    #pragma unroll
    for (int i = 0; i < 4; ++i) {
      int row = m0 + wm * 64 + i * 16 + ((lane >> 4) << 2);
      #pragma unroll
      for (int rr = 0; rr < 4; ++rr) {
        float hv = fmaxf(acc[i][j][0][rr] + bhv, 0.f);
        float gv = acc[i][j][1][rr] + bgv;
        float tv = 1.f / (1.f + expf(-gv));
        float xi = bf2f(xin[(size_t)(row + rr) * HIDD + col]);
        xout[(size_t)(row + rr) * HIDD + col] = f2bf(hv * tv + xi * (1.f - tv));
      }
    }
  }
}

// per-pair combine (bf16 partials, u16x8 vectors); descale before relu.
__global__ void pair_combine(const unsigned short* __restrict__ P, const int* __restrict__ newpos,
                             const int* __restrict__ idxx, const int* __restrict__ idxy,
                             unsigned short* __restrict__ xb) {
  int i = blockIdx.x * 256 + threadIdx.x;   // 4096 pairs x 64 col-groups (8 cols each)
  int p = i >> 6, c = i & 63;
  int rx = newpos[idxx[p]];
  int ry = newpos[idxy[p]];
  const size_t qs = (size_t)8192 * 512;
  const unsigned short* Px = P + (size_t)rx * 512 + c * 8;
  const unsigned short* Py = P + (size_t)ry * 512 + c * 8;
  float ax[8], ay[8];
  #pragma unroll
  for (int j = 0; j < 8; ++j) { ax[j] = 0.f; ay[j] = 0.f; }
  #pragma unroll
  for (int q = 0; q < KSPLIT; ++q) {
    u16x8 vx = *(const u16x8*)(Px + q * qs);
    u16x8 vy = *(const u16x8*)(Py + q * qs);
    #pragma unroll
    for (int j = 0; j < 8; ++j) { ax[j] += bf2f(vx[j]); ay[j] += bf2f(vy[j]); }
  }
  const float s = 0.04419417382415922f;    // 1/sqrt(512)
  u16x8 o;
  #pragma unroll
  for (int j = 0; j < 8; ++j) {
    float ex = fmaxf(ax[j] * INVSC, 0.f);
    float ey = fmaxf(ay[j] * INVSC, 0.f);
    float d = ex - ey;
    o[j] = f2bf(d * d * s);
  }
  *(u16x8*)(xb + (size_t)i * 8) = o;
}

// logits + 2-class log_softmax, one wave per row
__global__ void logits_lsm(const unsigned short* __restrict__ x2, const float* __restrict__ Wl,
                           const float* __restrict__ bl, float* __restrict__ out) {
  int gw = (blockIdx.x * blockDim.x + threadIdx.x) >> 6;
  int lane = threadIdx.x & 63;
  const unsigned short* xr = x2 + (size_t)gw * HIDD;
  u16x8 xv = *(const u16x8*)(xr + lane * 8);
  float4 w0 = ((const float4*)Wl)[lane * 4 + 0];
  float4 w1 = ((const float4*)Wl)[lane * 4 + 1];
  float4 w2 = ((const float4*)Wl)[lane * 4 + 2];
  float4 w3 = ((const float4*)Wl)[lane * 4 + 3];
  float xs[8];
  #pragma unroll
  for (int j = 0; j < 8; ++j) xs[j] = bf2f(xv[j]);
  float s0 = xs[0]*w0.x + xs[1]*w0.z + xs[2]*w1.x + xs[3]*w1.z
           + xs[4]*w2.x + xs[5]*w2.z + xs[6]*w3.x + xs[7]*w3.z;
  float s1 = xs[0]*w0.y + xs[1]*w0.w + xs[2]*w1.y + xs[3]*w1.w
           + xs[4]*w2.y + xs[5]*w2.w + xs[6]*w3.y + xs[7]*w3.w;
  #pragma unroll
  for (int off = 32; off; off >>= 1) { s0 += __shfl_down(s0, off); s1 += __shfl_down(s1, off); }
  if (lane == 0) {
    float l0 = s0 + bl[0], l1 = s1 + bl[1];
    float mx = fmaxf(l0, l1);
    float lse = mx + logf(expf(l0 - mx) + expf(l1 - mx));
    out[(size_t)gw * 2 + 0] = l0 - lse;
    out[(size_t)gw * 2 + 1] = l1 - lse;
  }
}

extern "C" void kernel_launch(void* const* d_in, const int* in_sizes, int n_in,
                              void* d_out, int out_size, void* d_ws, size_t ws_size,
                              hipStream_t stream) {
  const float* A   = (const float*)d_in[0];
  const float* W1  = (const float*)d_in[1];
  const float* Wh0 = (const float*)d_in[2];
  const float* bh0 = (const float*)d_in[3];
  const float* Wg0 = (const float*)d_in[4];
  const float* bg0 = (const float*)d_in[5];
  const float* Wh1 = (const float*)d_in[6];
  const float* bh1 = (const float*)d_in[7];
  const float* Wg1 = (const float*)d_in[8];
  const float* bg1 = (const float*)d_in[9];
  const float* Wl  = (const float*)d_in[10];
  const float* bl  = (const float*)d_in[11];
  const int* idxx  = (const int*)d_in[12];
  const int* idxy  = (const int*)d_in[13];
  float* out = (float*)d_out;

  char* w = (char*)d_ws;
  auto carve = [&](size_t bytes) { char* p = w; w += (bytes + 255) & ~(size_t)255; return p; };
  unsigned char* W1T8  = (unsigned char*)carve((size_t)512 * KPAD);
  unsigned short* WcT0 = (unsigned short*)carve((size_t)1024 * 512 * 2);
  unsigned short* WcT1 = (unsigned short*)carve((size_t)1024 * 512 * 2);
  unsigned short* Ppart= (unsigned short*)carve((size_t)KSPLIT * 8192 * 512 * 2);
  unsigned short* xb0  = (unsigned short*)carve((size_t)4096 * 512 * 2);
  unsigned short* xb1  = (unsigned short*)carve((size_t)4096 * 512 * 2);
  unsigned short* xb2  = (unsigned short*)carve((size_t)4096 * 512 * 2);
  int* newpos          = (int*)carve((size_t)KPAD * 4);
  int* rows            = (int*)carve((size_t)8256 * 4);
  int* nuniq           = (int*)carve(256);

  // weight prep + dedup
  prep_weights<<<dim3(6048), 256, 0, stream>>>(W1, W1T8, Wh0, Wg0, Wh1, Wg1,
      WcT0, WcT0 + (size_t)512 * 512, WcT1, WcT1 + (size_t)512 * 512);
  dedup_all<<<dim3(1), 1024, 0, stream>>>(idxx, idxy, newpos, rows, nuniq);

  // Ppart[ksp] (bf16) = (A[unique rows]*16) @ (W1*64) K-chunk (fp8, BK=64, dbuf)
  gather_gemm<<<dim3(KSPLIT, 128), 512, 0, stream>>>(A, W1T8, Ppart, rows, nuniq);
  pair_combine<<<dim3(1024), 256, 0, stream>>>(Ppart, newpos, idxx, idxy, xb0);

  // fused highway layers
  hwy_gemm<<<dim3(8, 32), 256, 0, stream>>>(xb0, WcT0, bh0, bg0, xb1);
  hwy_gemm<<<dim3(8, 32), 256, 0, stream>>>(xb1, WcT1, bh1, bg1, xb2);

  logits_lsm<<<dim3(1024), 256, 0, stream>>>(xb2, Wl, bl, out);
}

// Round 12
// 146.903 us; speedup vs baseline: 1.0536x; 1.0536x over previous
//
#include <hip/hip_runtime.h>
#include <hip/hip_bf16.h>
#include <math.h>

#define NN    10000
#define HIDD  512
#define BP    4096
#define KPAD2 10112     // 79 * 128  (fp8 gather GEMM, BK=128)
#define NK2   79
#define KSPLIT 5
#define ASCALE 16.0f
#define BSCALE 64.0f
#define INVSC  0.0009765625f   // 1/(16*64)

typedef short bf16x8 __attribute__((ext_vector_type(8)));
typedef float f32x4  __attribute__((ext_vector_type(4)));
typedef unsigned short u16x4 __attribute__((ext_vector_type(4)));
typedef unsigned short u16x8 __attribute__((ext_vector_type(8)));
typedef int   i32x4  __attribute__((ext_vector_type(4)));

__device__ __forceinline__ unsigned short f2bf(float f) {
  union { float f; unsigned u; } v; v.f = f;
  unsigned r = v.u + 0x7FFFu + ((v.u >> 16) & 1u);   // RN-even
  return (unsigned short)(r >> 16);
}
__device__ __forceinline__ float bf2f(unsigned short u) {
  union { unsigned u; float f; } v; v.u = ((unsigned)u) << 16;
  return v.f;
}
__device__ __forceinline__ void gload_lds16(const void* g, void* l) {
  __builtin_amdgcn_global_load_lds((const __attribute__((address_space(1))) unsigned int*)g,
                                   (__attribute__((address_space(3))) unsigned int*)l, 16, 0, 0);
}

// pack 2 f32 -> 2 fp8 e4m3 into low (hi=false) or high (hi=true) 16 bits of `old`
__device__ __forceinline__ int f2fp8pair(float a, float b, int old, bool hi) {
#if __has_builtin(__builtin_amdgcn_cvt_pk_fp8_f32)
  return hi ? __builtin_amdgcn_cvt_pk_fp8_f32(a, b, old, true)
            : __builtin_amdgcn_cvt_pk_fp8_f32(a, b, old, false);
#else
  auto cv = [](float x) -> unsigned {
    float c = fminf(fmaxf(x, -448.f), 448.f);
    union { float f; unsigned u; } v; v.f = c;
    unsigned sign = (v.u >> 24) & 0x80u;
    unsigned absu = v.u & 0x7FFFFFFFu;
    if (absu < 0x3B800000u) {
      int q = (int)rintf(fabsf(c) * 512.f);
      if (q > 7) q = 7;
      return sign | (unsigned)q;
    }
    unsigned r = absu + 0x00080000u + ((absu >> 20) & 1u);
    int e = (int)((r >> 23) & 0xFF) - 127;
    unsigned m = (r >> 20) & 7u;
    if (e > 8) return sign | 0x7Eu;
    if (e < -6) { int q = (int)rintf(fabsf(c) * 512.f); if (q > 7) q = 7; return sign | (unsigned)q; }
    return sign | ((unsigned)(e + 7) << 3) | m;
  };
  unsigned w = cv(a) | (cv(b) << 8);
  return hi ? ((old & 0xFFFF) | (int)(w << 16)) : (int)(((unsigned)old & 0xFFFF0000u) | w);
#endif
}

// Merged weight prep + dedup (flattened 1-D grid, 256 threads):
//  bid < 5056            : W1 f32 [NN][512] -> fp8 e4m3 (x BSCALE) [512][KPAD2]
//  5056 <= bid < 6080    : 4x 512x512 transpose+cvt bf16 (highway weights)
//  bid == 6080           : dedup (flags -> scan -> compact), 256 threads
__global__ void prep_weights(const float* __restrict__ W1, unsigned char* __restrict__ W1T8,
                             const float* __restrict__ s0, const float* __restrict__ s1,
                             const float* __restrict__ s2, const float* __restrict__ s3,
                             unsigned short* __restrict__ d0, unsigned short* __restrict__ d1,
                             unsigned short* __restrict__ d2, unsigned short* __restrict__ d3,
                             const int* __restrict__ idxx, const int* __restrict__ idxy,
                             int* __restrict__ newpos, int* __restrict__ rows,
                             int* __restrict__ nuniq) {
  __shared__ float tile[32][33];
  __shared__ unsigned char flag[10240];
  __shared__ int part[256];
  int bid = blockIdx.x;
  int t = threadIdx.x, c = t & 31, r = t >> 5;
  if (bid < 5056) {                       // W1 -> fp8: 316 k-tiles x 16 n-tiles
    int k0 = (bid % 316) * 32, n0 = (bid / 316) * 32;
    #pragma unroll
    for (int i = 0; i < 4; ++i) {
      int k = k0 + r + i * 8;
      tile[r + i * 8][c] = (k < NN) ? W1[(size_t)k * 512 + (n0 + c)] : 0.f;
    }
    __syncthreads();
    int c2 = t & 15, rn = t >> 4;
    #pragma unroll
    for (int i = 0; i < 2; ++i) {
      int n = rn + i * 16;
      int w = f2fp8pair(tile[2 * c2][n] * BSCALE, tile[2 * c2 + 1][n] * BSCALE, 0, false);
      *(unsigned short*)(W1T8 + (size_t)(n0 + n) * KPAD2 + k0 + 2 * c2) = (unsigned short)(w & 0xFFFF);
    }
  } else if (bid < 6080) {                // highway weights -> bf16 transpose
    int q = bid - 5056;
    int wsel = q >> 8, rr2 = q & 255;
    const float* src = (wsel == 0) ? s0 : (wsel == 1) ? s1 : (wsel == 2) ? s2 : s3;
    unsigned short* dst = (wsel == 0) ? d0 : (wsel == 1) ? d1 : (wsel == 2) ? d2 : d3;
    int k0 = (rr2 & 15) * 32, n0 = (rr2 >> 4) * 32;
    #pragma unroll
    for (int i = 0; i < 4; ++i)
      tile[r + i * 8][c] = src[(size_t)(k0 + r + i * 8) * 512 + (n0 + c)];
    __syncthreads();
    #pragma unroll
    for (int i = 0; i < 4; ++i)
      dst[(size_t)(n0 + r + i * 8) * 512 + (k0 + c)] = f2bf(tile[c][r + i * 8]);
  } else {                                // dedup with 256 threads
    #pragma unroll
    for (int j = 0; j < 10; ++j)
      ((int*)flag)[t + j * 256] = 0;      // 2560 ints
    __syncthreads();
    #pragma unroll
    for (int j = 0; j < 16; ++j) {
      flag[idxx[t + j * 256]] = 1;
      flag[idxy[t + j * 256]] = 1;
    }
    __syncthreads();
    int base = t * 40;                    // 40 elems/thread covers 10240
    int loc[40]; int s = 0;
    #pragma unroll
    for (int j = 0; j < 40; ++j) {
      int f = (base + j < NN) ? (int)flag[base + j] : 0;
      loc[j] = s; s += f;
    }
    part[t] = s;
    __syncthreads();
    for (int off = 1; off < 256; off <<= 1) {
      int v = (t >= off) ? part[t - off] : 0;
      __syncthreads();
      part[t] += v;
      __syncthreads();
    }
    int pre = (t == 0) ? 0 : part[t - 1];
    #pragma unroll
    for (int j = 0; j < 40; ++j) {
      int idx = base + j;
      if (idx < NN) {
        int pos = pre + loc[j];
        newpos[idx] = pos;
        if (flag[idx]) rows[pos] = idx;
      }
    }
    if (t == 255) nuniq[0] = part[255];
  }
}

// FP8 Gather-GEMM: Ppart[ksp][row][512] (bf16) = (A[rows]*16) @ (W1T*64)^T over K-chunk.
// Tile 64m x 512n x BK=128 fp8; 512 threads = 8 waves, wave-tile 64x64; 72 KB LDS,
// 2 blocks/CU; 3-barrier schedule (round-10 known-good).
__global__ __launch_bounds__(512, 4)
void gather_gemm(const float* __restrict__ A, const unsigned char* __restrict__ BT8,
                 unsigned short* __restrict__ Ppart,
                 const int* __restrict__ rows, const int* __restrict__ nuniq_p) {
  __shared__ __align__(16) char As[64 * 128];
  __shared__ __align__(16) char Bs[512 * 128];
  const int nuniq = nuniq_p[0];
  const int m0 = blockIdx.y * 64;
  if (m0 >= nuniq) return;
  const int tid  = threadIdx.x;
  const int lane = tid & 63;
  const int wave = tid >> 6;
  const int ksp  = blockIdx.x;
  const int t0   = (ksp * NK2) / KSPLIT;
  const int t1   = ((ksp + 1) * NK2) / KSPLIT;

  const int sr = tid >> 3, sp = tid & 7;
  int m = m0 + sr;
  int g = rows[(m < nuniq) ? m : (nuniq - 1)];
  const float* arow = A + (size_t)g * NN;

  const unsigned char* bsrc0 =
      BT8 + (size_t)(wave * 64 + (lane >> 3)) * KPAD2 + (((lane & 7) ^ (lane >> 3)) << 4);
  char* bdst0 = Bs + (wave << 13);

  f32x4 acc[4][4];
  #pragma unroll
  for (int i = 0; i < 4; ++i)
    #pragma unroll
    for (int j = 0; j < 4; ++j) acc[i][j] = (f32x4){0.f, 0.f, 0.f, 0.f};

  float4 ar[4];

  auto LOADA = [&](int t) {
    int ka = t * 128 + sp * 16;
    if (ka < NN) {
      #pragma unroll
      for (int j = 0; j < 4; ++j) ar[j] = *(const float4*)(arow + ka + j * 4);
    } else {
      #pragma unroll
      for (int j = 0; j < 4; ++j) ar[j] = make_float4(0.f, 0.f, 0.f, 0.f);
    }
  };
  auto ISSUEB = [&](int t) {
    const unsigned char* s = bsrc0 + (size_t)t * 128;
    #pragma unroll
    for (int j = 0; j < 8; ++j)
      gload_lds16(s + (size_t)j * 8 * KPAD2, bdst0 + j * 1024);
  };
  auto WRITEA = [&]() {
    i32x4 o;
    #pragma unroll
    for (int q = 0; q < 4; ++q) {
      int w = f2fp8pair(ar[q].x * ASCALE, ar[q].y * ASCALE, 0, false);
      w     = f2fp8pair(ar[q].z * ASCALE, ar[q].w * ASCALE, w, true);
      o[q] = w;
    }
    *(i32x4*)(As + sr * 128 + ((sp ^ (sr & 7)) << 4)) = o;
  };

  LOADA(t0);
  ISSUEB(t0);
  for (int t = t0; t < t1; ++t) {
    if (t > t0) __syncthreads();
    WRITEA();
    __syncthreads();
    if (t + 1 < t1) LOADA(t + 1);
    #pragma unroll
    for (int ks = 0; ks < 4; ++ks) {
      int kq  = lane >> 4;
      int G   = ks * 2 + (kq >> 1);
      int inn = (kq & 1) << 3;
      long aL[4]; long bL[4];
      #pragma unroll
      for (int i = 0; i < 4; ++i) {
        int r = i * 16 + (lane & 15);
        aL[i] = *(const long*)(As + r * 128 + ((G ^ (r & 7)) << 4) + inn);
      }
      #pragma unroll
      for (int j = 0; j < 4; ++j) {
        int n = wave * 64 + j * 16 + (lane & 15);
        bL[j] = *(const long*)(Bs + n * 128 + ((G ^ (n & 7)) << 4) + inn);
      }
      #pragma unroll
      for (int i = 0; i < 4; ++i)
        #pragma unroll
        for (int j = 0; j < 4; ++j)
          acc[i][j] = __builtin_amdgcn_mfma_f32_16x16x32_fp8_fp8(aL[i], bL[j], acc[i][j], 0, 0, 0);
    }
    __syncthreads();
    if (t + 1 < t1) ISSUEB(t + 1);
  }

  unsigned short* Cb = Ppart + (size_t)ksp * (8192 * 512);
  #pragma unroll
  for (int i = 0; i < 4; ++i) {
    #pragma unroll
    for (int j = 0; j < 4; ++j) {
      int row = m0 + i * 16 + ((lane >> 4) << 2);
      int col = wave * 64 + j * 16 + (lane & 15);
      #pragma unroll
      for (int rr = 0; rr < 4; ++rr)
        Cb[(size_t)(row + rr) * 512 + col] = f2bf(acc[i][j][rr]);
    }
  }
}

// Fused highway layer (bf16)
__global__ __launch_bounds__(256)
void hwy_gemm(const unsigned short* __restrict__ xin, const unsigned short* __restrict__ WcT,
              const float* __restrict__ bh, const float* __restrict__ bg,
              unsigned short* __restrict__ xout) {
  __shared__ __align__(16) char As[128 * 128];
  __shared__ __align__(16) char Bs[128 * 128];
  const int tid  = threadIdx.x;
  const int lane = tid & 63;
  const int wave = tid >> 6;
  const int wm = wave >> 1, wn = wave & 1;
  const int m0 = blockIdx.y * 128;
  const int n0 = blockIdx.x * 64;

  const int sr = tid >> 1, sp = tid & 1;
  const unsigned short* arow16 = xin + (size_t)(m0 + sr) * HIDD;
  const int rb = tid >> 1;
  const int grow = (rb < 64) ? (n0 + rb) : (512 + n0 + rb - 64);
  const unsigned short* brow = WcT + (size_t)grow * HIDD;

  f32x4 acc[4][2][2];
  #pragma unroll
  for (int i = 0; i < 4; ++i)
    #pragma unroll
    for (int j = 0; j < 2; ++j)
      #pragma unroll
      for (int p = 0; p < 2; ++p) acc[i][j][p] = (f32x4){0.f, 0.f, 0.f, 0.f};

  u16x8 ar16[4], br16[4];

  auto LOADREGS = [&](int t) {
    int k0 = t * 64;
    #pragma unroll
    for (int j = 0; j < 4; ++j)
      ar16[j] = *(const u16x8*)(arow16 + k0 + (sp * 4 + j) * 8);
    #pragma unroll
    for (int q = 0; q < 4; ++q)
      br16[q] = *(const u16x8*)(brow + k0 + (sp * 4 + q) * 8);
  };
  auto WRITELDS = [&]() {
    #pragma unroll
    for (int j = 0; j < 4; ++j) {
      int gq = sp * 4 + j;
      *(u16x8*)(As + sr * 128 + ((gq ^ (sr & 7)) << 4)) = ar16[j];
    }
    #pragma unroll
    for (int q = 0; q < 4; ++q) {
      int gq = sp * 4 + q;
      *(u16x8*)(Bs + rb * 128 + ((gq ^ (rb & 7)) << 4)) = br16[q];
    }
  };

  for (int t = 0; t < 8; ++t) {
    if (t == 0) LOADREGS(0);
    else __syncthreads();
    WRITELDS();
    if (t + 1 < 8) LOADREGS(t + 1);
    __syncthreads();
    #pragma unroll
    for (int ks = 0; ks < 2; ++ks) {
      bf16x8 af[4]; bf16x8 bfr[2][2];
      int kg = ks * 4 + (lane >> 4);
      #pragma unroll
      for (int i = 0; i < 4; ++i) {
        int r = wm * 64 + i * 16 + (lane & 15);
        af[i] = *(const bf16x8*)(As + r * 128 + ((kg ^ (r & 7)) << 4));
      }
      #pragma unroll
      for (int j = 0; j < 2; ++j)
        #pragma unroll
        for (int p = 0; p < 2; ++p) {
          int n = p * 64 + wn * 32 + j * 16 + (lane & 15);
          bfr[j][p] = *(const bf16x8*)(Bs + n * 128 + ((kg ^ (n & 7)) << 4));
        }
      #pragma unroll
      for (int i = 0; i < 4; ++i)
        #pragma unroll
        for (int j = 0; j < 2; ++j)
          #pragma unroll
          for (int p = 0; p < 2; ++p)
            acc[i][j][p] = __builtin_amdgcn_mfma_f32_16x16x32_bf16(af[i], bfr[j][p], acc[i][j][p], 0, 0, 0);
    }
  }

  #pragma unroll
  for (int j = 0; j < 2; ++j) {
    int col = n0 + wn * 32 + j * 16 + (lane & 15);
    float bhv = bh[col], bgv = bg[col];
    #pragma unroll
    for (int i = 0; i < 4; ++i) {
      int row = m0 + wm * 64 + i * 16 + ((lane >> 4) << 2);
      #pragma unroll
      for (int rr = 0; rr < 4; ++rr) {
        float hv = fmaxf(acc[i][j][0][rr] + bhv, 0.f);
        float gv = acc[i][j][1][rr] + bgv;
        float tv = 1.f / (1.f + expf(-gv));
        float xi = bf2f(xin[(size_t)(row + rr) * HIDD + col]);
        xout[(size_t)(row + rr) * HIDD + col] = f2bf(hv * tv + xi * (1.f - tv));
      }
    }
  }
}

// per-pair combine (bf16 partials, u16x8 vectors); descale before relu.
__global__ void pair_combine(const unsigned short* __restrict__ P, const int* __restrict__ newpos,
                             const int* __restrict__ idxx, const int* __restrict__ idxy,
                             unsigned short* __restrict__ xb) {
  int i = blockIdx.x * 256 + threadIdx.x;   // 4096 pairs x 64 col-groups (8 cols each)
  int p = i >> 6, c = i & 63;
  int rx = newpos[idxx[p]];
  int ry = newpos[idxy[p]];
  const size_t qs = (size_t)8192 * 512;
  const unsigned short* Px = P + (size_t)rx * 512 + c * 8;
  const unsigned short* Py = P + (size_t)ry * 512 + c * 8;
  float ax[8], ay[8];
  #pragma unroll
  for (int j = 0; j < 8; ++j) { ax[j] = 0.f; ay[j] = 0.f; }
  #pragma unroll
  for (int q = 0; q < KSPLIT; ++q) {
    u16x8 vx = *(const u16x8*)(Px + q * qs);
    u16x8 vy = *(const u16x8*)(Py + q * qs);
    #pragma unroll
    for (int j = 0; j < 8; ++j) { ax[j] += bf2f(vx[j]); ay[j] += bf2f(vy[j]); }
  }
  const float s = 0.04419417382415922f;    // 1/sqrt(512)
  u16x8 o;
  #pragma unroll
  for (int j = 0; j < 8; ++j) {
    float ex = fmaxf(ax[j] * INVSC, 0.f);
    float ey = fmaxf(ay[j] * INVSC, 0.f);
    float d = ex - ey;
    o[j] = f2bf(d * d * s);
  }
  *(u16x8*)(xb + (size_t)i * 8) = o;
}

// logits + 2-class log_softmax, one wave per row
__global__ void logits_lsm(const unsigned short* __restrict__ x2, const float* __restrict__ Wl,
                           const float* __restrict__ bl, float* __restrict__ out) {
  int gw = (blockIdx.x * blockDim.x + threadIdx.x) >> 6;
  int lane = threadIdx.x & 63;
  const unsigned short* xr = x2 + (size_t)gw * HIDD;
  u16x8 xv = *(const u16x8*)(xr + lane * 8);
  float4 w0 = ((const float4*)Wl)[lane * 4 + 0];
  float4 w1 = ((const float4*)Wl)[lane * 4 + 1];
  float4 w2 = ((const float4*)Wl)[lane * 4 + 2];
  float4 w3 = ((const float4*)Wl)[lane * 4 + 3];
  float xs[8];
  #pragma unroll
  for (int j = 0; j < 8; ++j) xs[j] = bf2f(xv[j]);
  float s0 = xs[0]*w0.x + xs[1]*w0.z + xs[2]*w1.x + xs[3]*w1.z
           + xs[4]*w2.x + xs[5]*w2.z + xs[6]*w3.x + xs[7]*w3.z;
  float s1 = xs[0]*w0.y + xs[1]*w0.w + xs[2]*w1.y + xs[3]*w1.w
           + xs[4]*w2.y + xs[5]*w2.w + xs[6]*w3.y + xs[7]*w3.w;
  #pragma unroll
  for (int off = 32; off; off >>= 1) { s0 += __shfl_down(s0, off); s1 += __shfl_down(s1, off); }
  if (lane == 0) {
    float l0 = s0 + bl[0], l1 = s1 + bl[1];
    float mx = fmaxf(l0, l1);
    float lse = mx + logf(expf(l0 - mx) + expf(l1 - mx));
    out[(size_t)gw * 2 + 0] = l0 - lse;
    out[(size_t)gw * 2 + 1] = l1 - lse;
  }
}

extern "C" void kernel_launch(void* const* d_in, const int* in_sizes, int n_in,
                              void* d_out, int out_size, void* d_ws, size_t ws_size,
                              hipStream_t stream) {
  const float* A   = (const float*)d_in[0];
  const float* W1  = (const float*)d_in[1];
  const float* Wh0 = (const float*)d_in[2];
  const float* bh0 = (const float*)d_in[3];
  const float* Wg0 = (const float*)d_in[4];
  const float* bg0 = (const float*)d_in[5];
  const float* Wh1 = (const float*)d_in[6];
  const float* bh1 = (const float*)d_in[7];
  const float* Wg1 = (const float*)d_in[8];
  const float* bg1 = (const float*)d_in[9];
  const float* Wl  = (const float*)d_in[10];
  const float* bl  = (const float*)d_in[11];
  const int* idxx  = (const int*)d_in[12];
  const int* idxy  = (const int*)d_in[13];
  float* out = (float*)d_out;

  char* w = (char*)d_ws;
  auto carve = [&](size_t bytes) { char* p = w; w += (bytes + 255) & ~(size_t)255; return p; };
  unsigned char* W1T8  = (unsigned char*)carve((size_t)512 * KPAD2);
  unsigned short* WcT0 = (unsigned short*)carve((size_t)1024 * 512 * 2);
  unsigned short* WcT1 = (unsigned short*)carve((size_t)1024 * 512 * 2);
  unsigned short* Ppart= (unsigned short*)carve((size_t)KSPLIT * 8192 * 512 * 2);
  unsigned short* xb0  = (unsigned short*)carve((size_t)4096 * 512 * 2);
  unsigned short* xb1  = (unsigned short*)carve((size_t)4096 * 512 * 2);
  unsigned short* xb2  = (unsigned short*)carve((size_t)4096 * 512 * 2);
  int* newpos          = (int*)carve((size_t)KPAD2 * 4);
  int* rows            = (int*)carve((size_t)8256 * 4);
  int* nuniq           = (int*)carve(256);

  // weight prep + dedup fused in ONE launch (dedup = block 6080, runs in parallel)
  prep_weights<<<dim3(6081), 256, 0, stream>>>(W1, W1T8, Wh0, Wg0, Wh1, Wg1,
      WcT0, WcT0 + (size_t)512 * 512, WcT1, WcT1 + (size_t)512 * 512,
      idxx, idxy, newpos, rows, nuniq);

  // Ppart[ksp] (bf16) = (A[unique rows]*16) @ (W1*64) K-chunk (fp8, BK=128)
  gather_gemm<<<dim3(KSPLIT, 128), 512, 0, stream>>>(A, W1T8, Ppart, rows, nuniq);
  pair_combine<<<dim3(1024), 256, 0, stream>>>(Ppart, newpos, idxx, idxy, xb0);

  // fused highway layers
  hwy_gemm<<<dim3(8, 32), 256, 0, stream>>>(xb0, WcT0, bh0, bg0, xb1);
  hwy_gemm<<<dim3(8, 32), 256, 0, stream>>>(xb1, WcT1, bh1, bg1, xb2);

  logits_lsm<<<dim3(1024), 256, 0, stream>>>(xb2, Wl, bl, out);
}